// Round 2
// baseline (476.535 us; speedup 1.0000x reference)
//
#include <hip/hip_runtime.h>
#include <hip/hip_bf16.h>
#include <cstdint>
#include <cstddef>

// ---------------- types ----------------
typedef short bf16x8 __attribute__((ext_vector_type(8)));   // 8 bf16 in 4 VGPRs
typedef float f32x4  __attribute__((ext_vector_type(4)));

#define HH 512
#define PP 256
#define LL 4096
#define BBATCH 16
#define MM (BBATCH * LL)          // 65536
#define NCHUNK 128                // chunks per sequence
#define SCHUNK 32                 // timesteps per chunk  (NCHUNK*SCHUNK == LL)

__device__ __forceinline__ unsigned short f2bf(float f) {
  union { float f; unsigned u; } v; v.f = f;
  unsigned r = (v.u + 0x7FFFu + ((v.u >> 16) & 1u)) >> 16;
  return (unsigned short)r;
}
__device__ __forceinline__ float bf2f(unsigned short b) {
  return __uint_as_float(((unsigned)b) << 16);
}

__device__ __forceinline__ void async16(const void* g, void* l) {
  __builtin_amdgcn_global_load_lds(
      (const __attribute__((address_space(1))) unsigned*)g,
      (__attribute__((address_space(3))) unsigned*)l, 16, 0, 0);
}

// ---------------- K0a: per-channel params ----------------
__global__ void precompute_params(const float* __restrict__ llr_,
                                  const float* __restrict__ lim_,
                                  const float* __restrict__ lstep_,
                                  float* __restrict__ lam) {
  int p = threadIdx.x;
  if (p >= PP) return;
  float Lr = -expf(llr_[p]);
  float Li = lim_[p];
  float st = expf(lstep_[p]);
  float mag = expf(Lr * st);
  float ang = Li * st;
  float lbr = mag * cosf(ang);
  float lbi = mag * sinf(ang);
  float den = Lr * Lr + Li * Li;
  float nr = lbr - 1.f, ni = lbi;
  float cr = (nr * Lr + ni * Li) / den;
  float ci = (ni * Lr - nr * Li) / den;
  float m32 = expf(32.f * Lr * st);
  float a32r = m32 * cosf(32.f * ang);
  float a32i = m32 * sinf(32.f * ang);
  lam[p]            = lbr;
  lam[PP + p]       = lbi;
  lam[2 * PP + p]   = a32r;
  lam[3 * PP + p]   = a32i;
  lam[4 * PP + p]   = cr;
  lam[5 * PP + p]   = ci;
}

// ---------------- K0b: build bf16 weight matrices ----------------
__global__ void build_weights(const float* __restrict__ B_re,
                              const float* __restrict__ B_im,
                              const float* __restrict__ C_re,
                              const float* __restrict__ C_im,
                              const float* __restrict__ lam,
                              unsigned short* __restrict__ Bcat,
                              unsigned short* __restrict__ Ccat) {
  int bid = blockIdx.x;   // 0..1023
  int tid = threadIdx.x;  // 0..255
  if (bid < 512) {
    int n = bid;
    int p = (n < PP) ? n : n - PP;
    float cr = lam[4 * PP + p], ci = lam[5 * PP + p];
    for (int c = tid; c < HH; c += 256) {
      float br = B_re[(size_t)p * HH + c];
      float bi = B_im[(size_t)p * HH + c];
      float v = (n < PP) ? (cr * br - ci * bi) : (cr * bi + ci * br);
      Bcat[(size_t)n * HH + c] = f2bf(v);
    }
  } else {
    int h = bid - 512;
    for (int c = tid; c < HH; c += 256) {
      float v = (c < PP) ? 2.f * C_re[(size_t)h * PP + c]
                         : -2.f * C_im[(size_t)h * PP + (c - PP)];
      Ccat[(size_t)h * HH + c] = f2bf(v);
    }
  }
}

// ---------------- K0c: x -> bf16 ----------------
__global__ __launch_bounds__(256) void cvt_x_bf16(const float* __restrict__ x,
                                                  unsigned short* __restrict__ xb) {
  const float4* x4 = (const float4*)x;
  ushort4* o4 = (ushort4*)xb;
  int stride = 2048 * 256;
  for (int i = blockIdx.x * 256 + threadIdx.x; i < (MM * HH / 4); i += stride) {
    float4 v = x4[i];
    ushort4 o;
    o.x = f2bf(v.x); o.y = f2bf(v.y); o.z = f2bf(v.z); o.w = f2bf(v.w);
    o4[i] = o;
  }
}

// ---------------- GEMM core (128x128 tile, BK=64, 4 waves) ----------------
// A [M,512] bf16 row-major, Bt [512,512] bf16 row-major ("B^T" layout).
// XCD-bijective block swizzle: nwg=2048 = 8 XCD * 256, the 4 nt-blocks of
// one mt become consecutive logical ids on ONE XCD -> A-tile fetched once.
// LDS XOR-swizzle (T2): linear global_load_lds dest + inverse-swizzled
// global SOURCE + swizzled ds_read (byte ^= (row&7)<<4 within 128B row).
// EPI 0: write bf16 C (Bu).
// EPI 1: t = acc + x*D; y = gelu(t); z = x + y; write bf16 z (xf/Cout alias).
template <int EPI>
__global__ __launch_bounds__(256) void gemm_bt(const unsigned short* __restrict__ A,
                                               const unsigned short* __restrict__ Bt,
                                               const unsigned short* xf,
                                               const float* __restrict__ Dv,
                                               unsigned short* Cout) {
  __shared__ __align__(16) unsigned short Asl[128 * 64];
  __shared__ __align__(16) unsigned short Bsl[128 * 64];
  const int tid = threadIdx.x, lane = tid & 63, w = tid >> 6;
  // XCD swizzle (bijective: 2048 % 8 == 0)
  const int bid = blockIdx.x;
  const int logical = (bid & 7) * 256 + (bid >> 3);
  const int mt = logical >> 2, nt = logical & 3;
  const int m0 = mt * 128, n0 = nt * 128;
  const int r = lane & 15, g = lane >> 4;
  const int wm = (w >> 1) * 64, wn = (w & 1) * 64;

  const char* Ab = (const char*)A;
  const char* Bb = (const char*)Bt;
  char* AslB = (char*)Asl;
  char* BslB = (char*)Bsl;

  f32x4 acc[4][4];
#pragma unroll
  for (int a = 0; a < 4; ++a)
#pragma unroll
    for (int b = 0; b < 4; ++b) acc[a][b] = (f32x4){0.f, 0.f, 0.f, 0.f};

  const int swz = (r & 7) << 4;   // constant per lane (row&7 == r&7 for all frags)

  for (int kt = 0; kt < 512; kt += 64) {
#pragma unroll
    for (int j = 0; j < 4; ++j) {
      int idx = w * 4 + j;                 // 0..15
      int W = idx * 1024 + lane * 16;      // linear LDS byte offset (dest)
      int row = W >> 7;                    // tile row (128 B per row)
      int colb = (W & 127) ^ ((row & 7) << 4);   // inverse-swizzled col byte
      async16(Ab + (size_t)(m0 + row) * 1024 + kt * 2 + colb, AslB + W);
      async16(Bb + (size_t)(n0 + row) * 1024 + kt * 2 + colb, BslB + W);
    }
    asm volatile("s_waitcnt vmcnt(0)" ::: "memory");
    __syncthreads();
#pragma unroll
    for (int kk = 0; kk < 2; ++kk) {
      bf16x8 af[4], bv[4];
#pragma unroll
      for (int mi = 0; mi < 4; ++mi)
        af[mi] = *(const bf16x8*)(AslB + (wm + mi * 16 + r) * 128 +
                                  ((kk * 64 + g * 16) ^ swz));
#pragma unroll
      for (int ni = 0; ni < 4; ++ni)
        bv[ni] = *(const bf16x8*)(BslB + (wn + ni * 16 + r) * 128 +
                                  ((kk * 64 + g * 16) ^ swz));
#pragma unroll
      for (int mi = 0; mi < 4; ++mi)
#pragma unroll
        for (int ni = 0; ni < 4; ++ni)
          acc[mi][ni] = __builtin_amdgcn_mfma_f32_16x16x32_bf16(
              af[mi], bv[ni], acc[mi][ni], 0, 0, 0);
    }
    __syncthreads();
  }

#pragma unroll
  for (int mi = 0; mi < 4; ++mi) {
#pragma unroll
    for (int ni = 0; ni < 4; ++ni) {
      int col = n0 + wn + ni * 16 + r;
      float Dh = (EPI == 1) ? Dv[col] : 0.f;
#pragma unroll
      for (int j = 0; j < 4; ++j) {
        int row = m0 + wm + mi * 16 + g * 4 + j;
        float v = acc[mi][ni][j];
        if (EPI == 0) {
          Cout[(size_t)row * 512 + col] = f2bf(v);
        } else {
          float xv = bf2f(xf[(size_t)row * 512 + col]);   // read before write (alias)
          float t = v + xv * Dh;
          float u = 0.7978845608028654f * (t + 0.044715f * t * t * t);
          float e = __expf(2.f * u);
          float th = 1.f - 2.f / (e + 1.f);
          float y = 0.5f * t * (1.f + th);
          Cout[(size_t)row * 512 + col] = f2bf(xv + y);
        }
      }
    }
  }
}

// ---------------- scan pass A: per-chunk carries ----------------
__global__ __launch_bounds__(256) void scan_carry(const unsigned short* __restrict__ Bu,
                                                  const float* __restrict__ lam,
                                                  float* __restrict__ carry) {
  int bid = blockIdx.x;              // b*128 + c
  int b = bid >> 7, c = bid & 127;
  int p = threadIdx.x;
  float ar = lam[p], ai = lam[PP + p];
  float sr = 0.f, si = 0.f;
  size_t base = ((size_t)b * LL + (size_t)c * SCHUNK) * 512;
#pragma unroll
  for (int i = 0; i < SCHUNK; ++i) {
    float ur = bf2f(Bu[base + (size_t)i * 512 + p]);
    float ui = bf2f(Bu[base + (size_t)i * 512 + 256 + p]);
    float nr = ar * sr - ai * si + ur;
    float ni = ar * si + ai * sr + ui;
    sr = nr; si = ni;
  }
  carry[(size_t)bid * 512 + p] = sr;
  carry[(size_t)bid * 512 + 256 + p] = si;
}

// ---------------- scan pass B: sequential chain over chunks (-> exclusive) ----------------
__global__ void scan_chain(float* __restrict__ carry, const float* __restrict__ lam) {
  int b = blockIdx.x;    // 16
  int p = threadIdx.x;   // 256
  float a32r = lam[2 * PP + p], a32i = lam[3 * PP + p];
  float sr = 0.f, si = 0.f;
  for (int c = 0; c < NCHUNK; ++c) {
    size_t idx = (size_t)(b * NCHUNK + c) * 512;
    float cr = carry[idx + p], ci = carry[idx + 256 + p];
    carry[idx + p] = sr;                 // exclusive: state entering chunk c
    carry[idx + 256 + p] = si;
    float nr = cr + a32r * sr - a32i * si;
    float ni = ci + a32r * si + a32i * sr;
    sr = nr; si = ni;
  }
}

// ---------------- scan pass C: recompute with carry-in, write xs IN-PLACE ----------------
// Bu and xs are the SAME buffer (per-element read-then-write by the same thread).
__global__ __launch_bounds__(256) void scan_final(const unsigned short* Bu,
                                                  const float* __restrict__ lam,
                                                  const float* __restrict__ carry,
                                                  unsigned short* xs) {
  int bid = blockIdx.x;
  int b = bid >> 7, c = bid & 127;
  int p = threadIdx.x;
  float ar = lam[p], ai = lam[PP + p];
  size_t cidx = (size_t)bid * 512;
  float sr = carry[cidx + p], si = carry[cidx + 256 + p];
  size_t base = ((size_t)b * LL + (size_t)c * SCHUNK) * 512;
#pragma unroll
  for (int i = 0; i < SCHUNK; ++i) {
    float ur = bf2f(Bu[base + (size_t)i * 512 + p]);
    float ui = bf2f(Bu[base + (size_t)i * 512 + 256 + p]);
    float nr = ar * sr - ai * si + ur;
    float ni = ar * si + ai * sr + ui;
    sr = nr; si = ni;
    xs[base + (size_t)i * 512 + p] = f2bf(sr);
    xs[base + (size_t)i * 512 + 256 + p] = f2bf(si);
  }
}

// ---------------- LayerNorm: one wave per row ----------------
__global__ __launch_bounds__(256) void ln_kernel(const unsigned short* __restrict__ z,
                                                 const float* __restrict__ scale,
                                                 const float* __restrict__ bias,
                                                 float* __restrict__ out) {
  int tid = threadIdx.x, lane = tid & 63, wv = tid >> 6;
  int gw = blockIdx.x * 4 + wv;      // 0..8191
  int c0 = lane * 8;
  float sc[8], bi[8];
#pragma unroll
  for (int j = 0; j < 8; ++j) { sc[j] = scale[c0 + j]; bi[j] = bias[c0 + j]; }
  for (int row = gw; row < MM; row += 8192) {
    uint4 zv = *(const uint4*)(z + (size_t)row * 512 + c0);
    float f[8];
    f[0] = __uint_as_float(zv.x << 16); f[1] = __uint_as_float(zv.x & 0xFFFF0000u);
    f[2] = __uint_as_float(zv.y << 16); f[3] = __uint_as_float(zv.y & 0xFFFF0000u);
    f[4] = __uint_as_float(zv.z << 16); f[5] = __uint_as_float(zv.z & 0xFFFF0000u);
    f[6] = __uint_as_float(zv.w << 16); f[7] = __uint_as_float(zv.w & 0xFFFF0000u);
    float s = 0.f, s2 = 0.f;
#pragma unroll
    for (int j = 0; j < 8; ++j) { s += f[j]; s2 += f[j] * f[j]; }
#pragma unroll
    for (int o = 32; o; o >>= 1) {
      s += __shfl_xor(s, o, 64);
      s2 += __shfl_xor(s2, o, 64);
    }
    float mean = s * (1.f / 512.f);
    float var = s2 * (1.f / 512.f) - mean * mean;
    float inv = rsqrtf(var + 1e-6f);
    float o8[8];
#pragma unroll
    for (int j = 0; j < 8; ++j) o8[j] = (f[j] - mean) * inv * sc[j] + bi[j];
    float4* op = (float4*)(out + (size_t)row * 512 + c0);
    op[0] = make_float4(o8[0], o8[1], o8[2], o8[3]);
    op[1] = make_float4(o8[4], o8[5], o8[6], o8[7]);
  }
}

// ---------------- launcher ----------------
extern "C" void kernel_launch(void* const* d_in, const int* in_sizes, int n_in,
                              void* d_out, int out_size, void* d_ws, size_t ws_size,
                              hipStream_t stream) {
  const float* x    = (const float*)d_in[0];
  const float* llr  = (const float*)d_in[1];
  const float* lim  = (const float*)d_in[2];
  const float* B_re = (const float*)d_in[3];
  const float* B_im = (const float*)d_in[4];
  const float* C_re = (const float*)d_in[5];
  const float* C_im = (const float*)d_in[6];
  const float* Dv   = (const float*)d_in[7];
  const float* lstep= (const float*)d_in[8];
  const float* lnsc = (const float*)d_in[9];
  const float* lnbi = (const float*)d_in[10];
  float* out = (float*)d_out;

  char* ws = (char*)d_ws;
  // layout:
  //   [0, 64MB)        x_bf16  -> later overwritten by z (gemm2 epilogue)
  //   [64MB, 128MB)    Bu bf16 -> overwritten IN-PLACE by xs (scan_final)
  //   then Bcat (512KB), Ccat (512KB), lam (6KB), carry (4MB)
  unsigned short* xb   = (unsigned short*)(ws);
  unsigned short* bu   = (unsigned short*)(ws + 67108864);
  unsigned short* bcat = (unsigned short*)(ws + 134217728);
  unsigned short* ccat = (unsigned short*)(ws + 134742016);
  float* lam           = (float*)(ws + 135266304);
  float* carry         = (float*)(ws + 135272448);

  precompute_params<<<1, 256, 0, stream>>>(llr, lim, lstep, lam);
  build_weights<<<1024, 256, 0, stream>>>(B_re, B_im, C_re, C_im, lam, bcat, ccat);
  cvt_x_bf16<<<2048, 256, 0, stream>>>(x, xb);
  gemm_bt<0><<<2048, 256, 0, stream>>>(xb, bcat, nullptr, nullptr, bu);
  scan_carry<<<2048, 256, 0, stream>>>(bu, lam, carry);
  scan_chain<<<16, 256, 0, stream>>>(carry, lam);
  scan_final<<<2048, 256, 0, stream>>>(bu, lam, carry, bu);   // xs in-place over Bu
  gemm_bt<1><<<2048, 256, 0, stream>>>(bu, ccat, xb, Dv, xb); // A=xs, x res in bf16, z over xb
  ln_kernel<<<2048, 256, 0, stream>>>(xb, lnsc, lnbi, out);
}

// Round 3
// 472.838 us; speedup vs baseline: 1.0078x; 1.0078x over previous
//
#include <hip/hip_runtime.h>
#include <hip/hip_bf16.h>
#include <cstdint>
#include <cstddef>

// ---------------- types ----------------
typedef short bf16x8 __attribute__((ext_vector_type(8)));   // 8 bf16 in 4 VGPRs
typedef float f32x4  __attribute__((ext_vector_type(4)));

#define HH 512
#define PP 256
#define LL 4096
#define BBATCH 16
#define MM (BBATCH * LL)          // 65536
#define NCHUNK 128                // chunks per sequence
#define SCHUNK 32                 // timesteps per chunk
#define NGRP 16                   // chunk-groups per sequence
#define GCH 8                     // chunks per group (NGRP*GCH == NCHUNK)

__device__ __forceinline__ unsigned short f2bf(float f) {
  union { float f; unsigned u; } v; v.f = f;
  unsigned r = (v.u + 0x7FFFu + ((v.u >> 16) & 1u)) >> 16;
  return (unsigned short)r;
}
__device__ __forceinline__ float bf2f(unsigned short b) {
  return __uint_as_float(((unsigned)b) << 16);
}

__device__ __forceinline__ void async16(const void* g, void* l) {
  __builtin_amdgcn_global_load_lds(
      (const __attribute__((address_space(1))) unsigned*)g,
      (__attribute__((address_space(3))) unsigned*)l, 16, 0, 0);
}

// ---------------- K0a: per-channel params ----------------
// lam layout (floats): [0,256) a_re      [256,512) a_im      (Lambda_bar)
//                      [512,768) a32_re  [768,1024) a32_im   (a^32)
//                      [1024,1280) coef_re [1280,1536) coef_im
//                      [1536,1792) a256_re [1792,2048) a256_im (a^256)
__global__ void precompute_params(const float* __restrict__ llr_,
                                  const float* __restrict__ lim_,
                                  const float* __restrict__ lstep_,
                                  float* __restrict__ lam) {
  int p = threadIdx.x;
  if (p >= PP) return;
  float Lr = -expf(llr_[p]);
  float Li = lim_[p];
  float st = expf(lstep_[p]);
  float mag = expf(Lr * st);
  float ang = Li * st;
  float lbr = mag * cosf(ang);
  float lbi = mag * sinf(ang);
  float den = Lr * Lr + Li * Li;
  float nr = lbr - 1.f, ni = lbi;
  float cr = (nr * Lr + ni * Li) / den;
  float ci = (ni * Lr - nr * Li) / den;
  float m32 = expf(32.f * Lr * st);
  float a32r = m32 * cosf(32.f * ang);
  float a32i = m32 * sinf(32.f * ang);
  float m256 = expf(256.f * Lr * st);
  float a256r = m256 * cosf(256.f * ang);
  float a256i = m256 * sinf(256.f * ang);
  lam[p]            = lbr;
  lam[PP + p]       = lbi;
  lam[2 * PP + p]   = a32r;
  lam[3 * PP + p]   = a32i;
  lam[4 * PP + p]   = cr;
  lam[5 * PP + p]   = ci;
  lam[6 * PP + p]   = a256r;
  lam[7 * PP + p]   = a256i;
}

// ---------------- K0b: build bf16 weight matrices (INTERLEAVED re/im) ----
// Bcat [512 rows(n), 512 cols(h)]: row 2p = Re(B_bar[p,:]), row 2p+1 = Im.
// Ccat [512 rows(h), 512 cols(k)]: col 2p = 2*C_re[h,p], col 2p+1 = -2*C_im[h,p].
__global__ void build_weights(const float* __restrict__ B_re,
                              const float* __restrict__ B_im,
                              const float* __restrict__ C_re,
                              const float* __restrict__ C_im,
                              const float* __restrict__ lam,
                              unsigned short* __restrict__ Bcat,
                              unsigned short* __restrict__ Ccat) {
  int bid = blockIdx.x;   // 0..1023
  int tid = threadIdx.x;  // 0..255
  if (bid < 512) {
    int n = bid;
    int p = n >> 1;
    int is_re = !(n & 1);
    float cr = lam[4 * PP + p], ci = lam[5 * PP + p];
    for (int c = tid; c < HH; c += 256) {
      float br = B_re[(size_t)p * HH + c];
      float bi = B_im[(size_t)p * HH + c];
      float v = is_re ? (cr * br - ci * bi) : (cr * bi + ci * br);
      Bcat[(size_t)n * HH + c] = f2bf(v);
    }
  } else {
    int h = bid - 512;
    for (int c = tid; c < HH; c += 256) {
      int p = c >> 1;
      float v = !(c & 1) ? 2.f * C_re[(size_t)h * PP + p]
                         : -2.f * C_im[(size_t)h * PP + p];
      Ccat[(size_t)h * HH + c] = f2bf(v);
    }
  }
}

// ---------------- K0c: x -> bf16 ----------------
__global__ __launch_bounds__(256) void cvt_x_bf16(const float* __restrict__ x,
                                                  unsigned short* __restrict__ xb) {
  const float4* x4 = (const float4*)x;
  ushort4* o4 = (ushort4*)xb;
  int stride = 2048 * 256;
  for (int i = blockIdx.x * 256 + threadIdx.x; i < (MM * HH / 4); i += stride) {
    float4 v = x4[i];
    ushort4 o;
    o.x = f2bf(v.x); o.y = f2bf(v.y); o.z = f2bf(v.z); o.w = f2bf(v.w);
    o4[i] = o;
  }
}

// ---------------- GEMM: 2-phase pipelined, 128x128 tile, 4 mt-tiles/block ----
// A [M,512] bf16 row-major, Bt [512,512] bf16 row-major ("B^T" layout).
// Grid = 512 blocks (2/CU, all co-resident). Block owns nt and mg (4 mts).
// Flattened 32-step pipeline: STAGE(next) issued BEFORE compute(cur);
// vmcnt(0)+barrier only at step end (T3 minimum 2-phase recipe).
// LDS XOR-swizzle as verified in R2 (0 bank conflicts).
template <int EPI>
__global__ __launch_bounds__(256) void gemm_bt(const unsigned short* __restrict__ A,
                                               const unsigned short* __restrict__ Bt,
                                               const unsigned short* xf,
                                               const float* __restrict__ Dv,
                                               unsigned short* Cout) {
  __shared__ __align__(16) unsigned short As[2][8192];
  __shared__ __align__(16) unsigned short Bs[2][8192];
  const int tid = threadIdx.x, lane = tid & 63, w = tid >> 6;
  const int bid = blockIdx.x;                       // 0..511
  const int logical = (bid & 7) * 64 + (bid >> 3);  // XCD-bijective
  const int nt = logical & 3, mg = logical >> 2;    // mg 0..127
  const int n0 = nt * 128;
  const int r = lane & 15, g = lane >> 4;
  const int wm = (w >> 1) * 64, wn = (w & 1) * 64;
  const int swz = (r & 7) << 4;

  int sW[4], srow[4], scol[4];
#pragma unroll
  for (int j = 0; j < 4; ++j) {
    int idx = w * 4 + j;
    int W = idx * 1024 + lane * 16;
    sW[j] = W;
    srow[j] = W >> 7;
    scol[j] = (W & 127) ^ (((W >> 7) & 7) << 4);
  }
  const char* Ab = (const char*)A;
  const char* Bb = (const char*)Bt;
  char* As0 = (char*)&As[0][0];
  char* Bs0 = (char*)&Bs[0][0];

  f32x4 acc[4][4];
#pragma unroll
  for (int a2 = 0; a2 < 4; ++a2)
#pragma unroll
    for (int b2 = 0; b2 < 4; ++b2) acc[a2][b2] = (f32x4){0.f, 0.f, 0.f, 0.f};

#define STAGE_(buf_, s_) { \
    int m0_ = (mg * 4 + ((s_) >> 3)) * 128; \
    int kb_ = ((s_) & 7) * 128; \
    char* dA_ = As0 + (buf_) * 16384; \
    char* dB_ = Bs0 + (buf_) * 16384; \
    _Pragma("unroll") \
    for (int j = 0; j < 4; ++j) { \
      async16(Ab + (size_t)(m0_ + srow[j]) * 1024 + kb_ + scol[j], dA_ + sW[j]); \
      async16(Bb + (size_t)(n0  + srow[j]) * 1024 + kb_ + scol[j], dB_ + sW[j]); \
    } }

  STAGE_(0, 0);
  asm volatile("s_waitcnt vmcnt(0)" ::: "memory");
  __syncthreads();

  int cur = 0;
  for (int s = 0; s < 32; ++s) {
    if (s < 31) STAGE_(cur ^ 1, s + 1);    // issue next-step loads FIRST
    const char* rdA = As0 + cur * 16384;
    const char* rdB = Bs0 + cur * 16384;
#pragma unroll
    for (int kk = 0; kk < 2; ++kk) {
      bf16x8 af[4], bv[4];
#pragma unroll
      for (int mi = 0; mi < 4; ++mi)
        af[mi] = *(const bf16x8*)(rdA + (wm + mi * 16 + r) * 128 +
                                  ((kk * 64 + g * 16) ^ swz));
#pragma unroll
      for (int ni = 0; ni < 4; ++ni)
        bv[ni] = *(const bf16x8*)(rdB + (wn + ni * 16 + r) * 128 +
                                  ((kk * 64 + g * 16) ^ swz));
#pragma unroll
      for (int mi = 0; mi < 4; ++mi)
#pragma unroll
        for (int ni = 0; ni < 4; ++ni)
          acc[mi][ni] = __builtin_amdgcn_mfma_f32_16x16x32_bf16(
              af[mi], bv[ni], acc[mi][ni], 0, 0, 0);
    }
    if ((s & 7) == 7) {                    // end of one mt tile -> epilogue
      int m0 = (mg * 4 + (s >> 3)) * 128;
#pragma unroll
      for (int mi = 0; mi < 4; ++mi)
#pragma unroll
        for (int ni = 0; ni < 4; ++ni) {
          int col = n0 + wn + ni * 16 + r;
          float Dh = (EPI == 1) ? Dv[col] : 0.f;
#pragma unroll
          for (int j = 0; j < 4; ++j) {
            int row = m0 + wm + mi * 16 + g * 4 + j;
            float v = acc[mi][ni][j];
            if (EPI == 0) {
              Cout[(size_t)row * 512 + col] = f2bf(v);
            } else {
              float xv = bf2f(xf[(size_t)row * 512 + col]);  // read-before-write (alias)
              float t = v + xv * Dh;
              float u2 = 0.7978845608028654f * (t + 0.044715f * t * t * t);
              float e = __expf(2.f * u2);
              float th = 1.f - 2.f / (e + 1.f);
              float y = 0.5f * t * (1.f + th);
              Cout[(size_t)row * 512 + col] = f2bf(xv + y);
            }
            acc[mi][ni][j] = 0.f;          // reset for next mt tile
          }
        }
    }
    asm volatile("s_waitcnt vmcnt(0)" ::: "memory");
    __syncthreads();
    cur ^= 1;
  }
#undef STAGE_
}

// ---------------- scan pass A: per-chunk carries (interleaved Bu) ----------
__global__ __launch_bounds__(256) void scan_carry(const unsigned short* __restrict__ Bu,
                                                  const float* __restrict__ lam,
                                                  float* __restrict__ carry) {
  int bid = blockIdx.x;              // b*128 + c
  int b = bid >> 7, c = bid & 127;
  int p = threadIdx.x;
  float ar = lam[p], ai = lam[PP + p];
  float sr = 0.f, si = 0.f;
  size_t base = ((size_t)b * LL + (size_t)c * SCHUNK) * 512;
#pragma unroll
  for (int i = 0; i < SCHUNK; ++i) {
    unsigned u = ((const unsigned*)(Bu + base + (size_t)i * 512))[p];
    float ur = bf2f((unsigned short)(u & 0xFFFFu));
    float ui = bf2f((unsigned short)(u >> 16));
    float nr = ar * sr - ai * si + ur;
    float ni = ar * si + ai * sr + ui;
    sr = nr; si = ni;
  }
  ((float2*)(carry + (size_t)bid * 512))[p] = make_float2(sr, si);
}

// ---------------- hierarchical chunk-chain (depth 128 -> 8+16+8) ----------
__global__ void chain_a(const float* __restrict__ carry,
                        const float* __restrict__ lam,
                        float* __restrict__ gcarry) {
  int bid = blockIdx.x;              // b*16 + g2
  int b = bid >> 4, g2 = bid & 15;
  int p = threadIdx.x;
  float ar = lam[2 * PP + p], ai = lam[3 * PP + p];   // a^32
  float sr = 0.f, si = 0.f;
#pragma unroll
  for (int i = 0; i < GCH; ++i) {
    int c = g2 * GCH + i;
    float2 cv = ((const float2*)(carry + (size_t)(b * NCHUNK + c) * 512))[p];
    float nr = cv.x + ar * sr - ai * si;
    float ni = cv.y + ar * si + ai * sr;
    sr = nr; si = ni;
  }
  ((float2*)(gcarry + (size_t)bid * 512))[p] = make_float2(sr, si);
}

__global__ void chain_b(const float* __restrict__ gcarry,
                        const float* __restrict__ lam,
                        float* __restrict__ gstate) {
  int b = blockIdx.x;                // 16
  int p = threadIdx.x;
  float ar = lam[6 * PP + p], ai = lam[7 * PP + p];   // a^256
  float sr = 0.f, si = 0.f;
#pragma unroll
  for (int g2 = 0; g2 < NGRP; ++g2) {
    float2 cv = ((const float2*)(gcarry + (size_t)(b * NGRP + g2) * 512))[p];
    ((float2*)(gstate + (size_t)(b * NGRP + g2) * 512))[p] = make_float2(sr, si);
    float nr = cv.x + ar * sr - ai * si;
    float ni = cv.y + ar * si + ai * sr;
    sr = nr; si = ni;
  }
}

__global__ void chain_c(float* carry,
                        const float* __restrict__ lam,
                        const float* __restrict__ gstate) {
  int bid = blockIdx.x;              // b*16 + g2
  int b = bid >> 4, g2 = bid & 15;
  int p = threadIdx.x;
  float ar = lam[2 * PP + p], ai = lam[3 * PP + p];   // a^32
  float2 s0 = ((const float2*)(gstate + (size_t)bid * 512))[p];
  float sr = s0.x, si = s0.y;
#pragma unroll
  for (int i = 0; i < GCH; ++i) {
    int c = g2 * GCH + i;
    float2* slot = ((float2*)(carry + (size_t)(b * NCHUNK + c) * 512)) + p;
    float2 cv = *slot;
    *slot = make_float2(sr, si);     // exclusive state entering chunk c
    float nr = cv.x + ar * sr - ai * si;
    float ni = cv.y + ar * si + ai * sr;
    sr = nr; si = ni;
  }
}

// ---------------- scan pass C: recompute with carry-in, xs IN-PLACE over Bu --
__global__ __launch_bounds__(256) void scan_final(unsigned short* Bu,
                                                  const float* __restrict__ lam,
                                                  const float* __restrict__ carry) {
  int bid = blockIdx.x;
  int b = bid >> 7, c = bid & 127;
  int p = threadIdx.x;
  float ar = lam[p], ai = lam[PP + p];
  float2 s0 = ((const float2*)(carry + (size_t)bid * 512))[p];
  float sr = s0.x, si = s0.y;
  size_t base = ((size_t)b * LL + (size_t)c * SCHUNK) * 512;
#pragma unroll
  for (int i = 0; i < SCHUNK; ++i) {
    unsigned* slot = ((unsigned*)(Bu + base + (size_t)i * 512)) + p;
    unsigned u = *slot;
    float ur = bf2f((unsigned short)(u & 0xFFFFu));
    float ui = bf2f((unsigned short)(u >> 16));
    float nr = ar * sr - ai * si + ur;
    float ni = ar * si + ai * sr + ui;
    sr = nr; si = ni;
    *slot = (unsigned)f2bf(sr) | ((unsigned)f2bf(si) << 16);
  }
}

// ---------------- LayerNorm: one wave per row ----------------
__global__ __launch_bounds__(256) void ln_kernel(const unsigned short* __restrict__ z,
                                                 const float* __restrict__ scale,
                                                 const float* __restrict__ bias,
                                                 float* __restrict__ out) {
  int tid = threadIdx.x, lane = tid & 63, wv = tid >> 6;
  int gw = blockIdx.x * 4 + wv;      // 0..8191
  int c0 = lane * 8;
  float sc[8], bi[8];
#pragma unroll
  for (int j = 0; j < 8; ++j) { sc[j] = scale[c0 + j]; bi[j] = bias[c0 + j]; }
  for (int row = gw; row < MM; row += 8192) {
    uint4 zv = *(const uint4*)(z + (size_t)row * 512 + c0);
    float f[8];
    f[0] = __uint_as_float(zv.x << 16); f[1] = __uint_as_float(zv.x & 0xFFFF0000u);
    f[2] = __uint_as_float(zv.y << 16); f[3] = __uint_as_float(zv.y & 0xFFFF0000u);
    f[4] = __uint_as_float(zv.z << 16); f[5] = __uint_as_float(zv.z & 0xFFFF0000u);
    f[6] = __uint_as_float(zv.w << 16); f[7] = __uint_as_float(zv.w & 0xFFFF0000u);
    float s = 0.f, s2 = 0.f;
#pragma unroll
    for (int j = 0; j < 8; ++j) { s += f[j]; s2 += f[j] * f[j]; }
#pragma unroll
    for (int o = 32; o; o >>= 1) {
      s += __shfl_xor(s, o, 64);
      s2 += __shfl_xor(s2, o, 64);
    }
    float mean = s * (1.f / 512.f);
    float var = s2 * (1.f / 512.f) - mean * mean;
    float inv = rsqrtf(var + 1e-6f);
    float o8[8];
#pragma unroll
    for (int j = 0; j < 8; ++j) o8[j] = (f[j] - mean) * inv * sc[j] + bi[j];
    float4* op = (float4*)(out + (size_t)row * 512 + c0);
    op[0] = make_float4(o8[0], o8[1], o8[2], o8[3]);
    op[1] = make_float4(o8[4], o8[5], o8[6], o8[7]);
  }
}

// ---------------- launcher ----------------
extern "C" void kernel_launch(void* const* d_in, const int* in_sizes, int n_in,
                              void* d_out, int out_size, void* d_ws, size_t ws_size,
                              hipStream_t stream) {
  const float* x    = (const float*)d_in[0];
  const float* llr  = (const float*)d_in[1];
  const float* lim  = (const float*)d_in[2];
  const float* B_re = (const float*)d_in[3];
  const float* B_im = (const float*)d_in[4];
  const float* C_re = (const float*)d_in[5];
  const float* C_im = (const float*)d_in[6];
  const float* Dv   = (const float*)d_in[7];
  const float* lstep= (const float*)d_in[8];
  const float* lnsc = (const float*)d_in[9];
  const float* lnbi = (const float*)d_in[10];
  float* out = (float*)d_out;

  char* ws = (char*)d_ws;
  // layout:
  //   [0, 64MB)        x_bf16  -> later overwritten by z (gemm2 epilogue)
  //   [64MB, 128MB)    Bu bf16 (interleaved re/im) -> xs in-place
  //   bcat 512KB, ccat 512KB, lam 8KB, carry 4MB, gcarry 512KB, gstate 512KB
  unsigned short* xb   = (unsigned short*)(ws);
  unsigned short* bu   = (unsigned short*)(ws + 67108864);
  unsigned short* bcat = (unsigned short*)(ws + 134217728);
  unsigned short* ccat = (unsigned short*)(ws + 134742016);
  float* lam           = (float*)(ws + 135266304);
  float* carry         = (float*)(ws + 135274496);
  float* gcarry        = (float*)(ws + 139468800);
  float* gstate        = (float*)(ws + 139993088);

  precompute_params<<<1, 256, 0, stream>>>(llr, lim, lstep, lam);
  build_weights<<<1024, 256, 0, stream>>>(B_re, B_im, C_re, C_im, lam, bcat, ccat);
  cvt_x_bf16<<<2048, 256, 0, stream>>>(x, xb);
  gemm_bt<0><<<512, 256, 0, stream>>>(xb, bcat, nullptr, nullptr, bu);
  scan_carry<<<2048, 256, 0, stream>>>(bu, lam, carry);
  chain_a<<<256, 256, 0, stream>>>(carry, lam, gcarry);
  chain_b<<<16, 256, 0, stream>>>(gcarry, lam, gstate);
  chain_c<<<256, 256, 0, stream>>>(carry, lam, gstate);
  scan_final<<<2048, 256, 0, stream>>>(bu, lam, carry);       // xs in-place over Bu
  gemm_bt<1><<<512, 256, 0, stream>>>(bu, ccat, xb, Dv, xb);  // A=xs, z over xb
  ln_kernel<<<2048, 256, 0, stream>>>(xb, lnsc, lnbi, out);
}

// Round 4
// 435.683 us; speedup vs baseline: 1.0938x; 1.0853x over previous
//
#include <hip/hip_runtime.h>
#include <hip/hip_bf16.h>
#include <cstdint>
#include <cstddef>

// ---------------- types ----------------
typedef short bf16x8 __attribute__((ext_vector_type(8)));   // 8 bf16 in 4 VGPRs
typedef float f32x4  __attribute__((ext_vector_type(4)));

#define HH 512
#define PP 256
#define LL 4096
#define BBATCH 16
#define MM (BBATCH * LL)          // 65536
#define NCHUNK 128                // chunks per sequence
#define SCHUNK 32                 // timesteps per chunk

__device__ __forceinline__ unsigned short f2bf(float f) {
  union { float f; unsigned u; } v; v.f = f;
  unsigned r = (v.u + 0x7FFFu + ((v.u >> 16) & 1u)) >> 16;
  return (unsigned short)r;
}
__device__ __forceinline__ float bf2f(unsigned short b) {
  return __uint_as_float(((unsigned)b) << 16);
}

__device__ __forceinline__ void async16(const void* g, void* l) {
  __builtin_amdgcn_global_load_lds(
      (const __attribute__((address_space(1))) unsigned*)g,
      (__attribute__((address_space(3))) unsigned*)l, 16, 0, 0);
}

// ---------------- K0a: per-channel params ----------------
// lam layout (floats): [0,256) a_re   [256,512) a_im    (Lambda_bar)
//                      [512,768) a32_re [768,1024) a32_im (a^32)
//                      [1024,1280) coef_re [1280,1536) coef_im
__global__ void precompute_params(const float* __restrict__ llr_,
                                  const float* __restrict__ lim_,
                                  const float* __restrict__ lstep_,
                                  float* __restrict__ lam) {
  int p = threadIdx.x;
  if (p >= PP) return;
  float Lr = -expf(llr_[p]);
  float Li = lim_[p];
  float st = expf(lstep_[p]);
  float mag = expf(Lr * st);
  float ang = Li * st;
  float lbr = mag * cosf(ang);
  float lbi = mag * sinf(ang);
  float den = Lr * Lr + Li * Li;
  float nr = lbr - 1.f, ni = lbi;
  float cr = (nr * Lr + ni * Li) / den;
  float ci = (ni * Lr - nr * Li) / den;
  float m32 = expf(32.f * Lr * st);
  float a32r = m32 * cosf(32.f * ang);
  float a32i = m32 * sinf(32.f * ang);
  lam[p]            = lbr;
  lam[PP + p]       = lbi;
  lam[2 * PP + p]   = a32r;
  lam[3 * PP + p]   = a32i;
  lam[4 * PP + p]   = cr;
  lam[5 * PP + p]   = ci;
}

// ---------------- K0b: build bf16 weight matrices (INTERLEAVED re/im) ----
// Bcat [512 rows(n), 512 cols(h)]: row 2p = Re(B_bar[p,:]), row 2p+1 = Im.
// Ccat [512 rows(h), 512 cols(k)]: col 2p = 2*C_re[h,p], col 2p+1 = -2*C_im[h,p].
__global__ void build_weights(const float* __restrict__ B_re,
                              const float* __restrict__ B_im,
                              const float* __restrict__ C_re,
                              const float* __restrict__ C_im,
                              const float* __restrict__ lam,
                              unsigned short* __restrict__ Bcat,
                              unsigned short* __restrict__ Ccat) {
  int bid = blockIdx.x;   // 0..1023
  int tid = threadIdx.x;  // 0..255
  if (bid < 512) {
    int n = bid;
    int p = n >> 1;
    int is_re = !(n & 1);
    float cr = lam[4 * PP + p], ci = lam[5 * PP + p];
    for (int c = tid; c < HH; c += 256) {
      float br = B_re[(size_t)p * HH + c];
      float bi = B_im[(size_t)p * HH + c];
      float v = is_re ? (cr * br - ci * bi) : (cr * bi + ci * br);
      Bcat[(size_t)n * HH + c] = f2bf(v);
    }
  } else {
    int h = bid - 512;
    for (int c = tid; c < HH; c += 256) {
      int p = c >> 1;
      float v = !(c & 1) ? 2.f * C_re[(size_t)h * PP + p]
                         : -2.f * C_im[(size_t)h * PP + p];
      Ccat[(size_t)h * HH + c] = f2bf(v);
    }
  }
}

// ---------------- K0c: x -> bf16 ----------------
__global__ __launch_bounds__(256) void cvt_x_bf16(const float* __restrict__ x,
                                                  unsigned short* __restrict__ xb) {
  const float4* x4 = (const float4*)x;
  ushort4* o4 = (ushort4*)xb;
  int stride = 2048 * 256;
  for (int i = blockIdx.x * 256 + threadIdx.x; i < (MM * HH / 4); i += stride) {
    float4 v = x4[i];
    ushort4 o;
    o.x = f2bf(v.x); o.y = f2bf(v.y); o.z = f2bf(v.z); o.w = f2bf(v.w);
    o4[i] = o;
  }
}

// ---------------- GEMM: counted-vmcnt pipeline (T4), 128x128 tile ----------
// A [M,512] bf16 row-major, Bt [512,512] bf16 row-major ("B^T" layout).
// Grid 512 blocks (2/CU). Block owns nt and 4 consecutive mt tiles = 32 steps.
// Per step: STAGE(s+1) -> s_waitcnt vmcnt(8) (keeps s+1's 8 loads in flight
// for a FULL step of HBM latency) -> raw s_barrier -> ds_read+MFMA ->
// raw s_barrier -> (every 8th step) epilogue store.
// LDS XOR-swizzle as verified in R2 (0 bank conflicts).
__global__ __launch_bounds__(256) void gemm_bt(const unsigned short* __restrict__ A,
                                               const unsigned short* __restrict__ Bt,
                                               unsigned short* __restrict__ Cout) {
  __shared__ __align__(16) unsigned short As[2][8192];
  __shared__ __align__(16) unsigned short Bs[2][8192];
  const int tid = threadIdx.x, lane = tid & 63, w = tid >> 6;
  const int bid = blockIdx.x;                       // 0..511
  const int logical = (bid & 7) * 64 + (bid >> 3);  // XCD-bijective (512%8==0)
  const int nt = logical & 3, mg = logical >> 2;    // mg 0..127
  const int n0 = nt * 128;
  const int r = lane & 15, g = lane >> 4;
  const int wm = (w >> 1) * 64, wn = (w & 1) * 64;
  const int swz = (r & 7) << 4;

  // staging slots + incremental global pointers
  int sW[4];
  const char* pA[4];
  const char* pB[4];
  {
    const char* Ab = (const char*)A;
    const char* Bb = (const char*)Bt;
#pragma unroll
    for (int j = 0; j < 4; ++j) {
      int idx = w * 4 + j;
      int W = idx * 1024 + lane * 16;
      sW[j] = W;
      int row = W >> 7;
      int colb = (W & 127) ^ ((row & 7) << 4);
      pA[j] = Ab + (size_t)(mg * 512 + row) * 1024 + colb;  // step 0: m0=mg*512 rows, kb=0
      pB[j] = Bb + (size_t)(n0 + row) * 1024 + colb;
    }
  }
  char* As0 = (char*)&As[0][0];
  char* Bs0 = (char*)&Bs[0][0];

  f32x4 acc[4][4];
#pragma unroll
  for (int a2 = 0; a2 < 4; ++a2)
#pragma unroll
    for (int b2 = 0; b2 < 4; ++b2) acc[a2][b2] = (f32x4){0.f, 0.f, 0.f, 0.f};

#define STAGE_(buf_) { \
    char* dA_ = As0 + (buf_) * 16384; \
    char* dB_ = Bs0 + (buf_) * 16384; \
    _Pragma("unroll") \
    for (int j = 0; j < 4; ++j) { \
      async16(pA[j], dA_ + sW[j]); \
      async16(pB[j], dB_ + sW[j]); \
    } }
  // advance pointers so they address step (dest_)
#define ADV_(dest_) { \
    int dAi_ = (((dest_) & 7) == 0) ? 130176 : 128; \
    int dBi_ = (((dest_) & 7) == 0) ? -896 : 128; \
    _Pragma("unroll") \
    for (int j = 0; j < 4; ++j) { pA[j] += dAi_; pB[j] += dBi_; } }

  STAGE_(0);          // loads for step 0 in flight (8)
  ADV_(1);

  for (int s = 0; s < 32; ++s) {
    if (s < 31) {
      STAGE_((s + 1) & 1);     // issue next step's 8 loads (outstanding <= 16)
      ADV_(s + 2);
      asm volatile("s_waitcnt vmcnt(8)" ::: "memory");   // step-s loads done
    } else {
      asm volatile("s_waitcnt vmcnt(0)" ::: "memory");
    }
    __builtin_amdgcn_sched_barrier(0);
    __builtin_amdgcn_s_barrier();        // all waves' step-s loads landed
    __builtin_amdgcn_sched_barrier(0);

    const char* rdA = As0 + (s & 1) * 16384;
    const char* rdB = Bs0 + (s & 1) * 16384;
    __builtin_amdgcn_s_setprio(1);
#pragma unroll
    for (int kk = 0; kk < 2; ++kk) {
      bf16x8 af[4], bv[4];
#pragma unroll
      for (int mi = 0; mi < 4; ++mi)
        af[mi] = *(const bf16x8*)(rdA + (wm + mi * 16 + r) * 128 +
                                  ((kk * 64 + g * 16) ^ swz));
#pragma unroll
      for (int ni = 0; ni < 4; ++ni)
        bv[ni] = *(const bf16x8*)(rdB + (wn + ni * 16 + r) * 128 +
                                  ((kk * 64 + g * 16) ^ swz));
#pragma unroll
      for (int mi = 0; mi < 4; ++mi)
#pragma unroll
        for (int ni = 0; ni < 4; ++ni)
          acc[mi][ni] = __builtin_amdgcn_mfma_f32_16x16x32_bf16(
              af[mi], bv[ni], acc[mi][ni], 0, 0, 0);
    }
    __builtin_amdgcn_s_setprio(0);
    __builtin_amdgcn_sched_barrier(0);
    __builtin_amdgcn_s_barrier();        // all waves done reading buf(s&1)
    __builtin_amdgcn_sched_barrier(0);

    if ((s & 7) == 7) {                  // tile finished -> store (after barrier:
      int m0 = (mg * 4 + (s >> 3)) * 128;  // no LDS dependency)
#pragma unroll
      for (int mi = 0; mi < 4; ++mi)
#pragma unroll
        for (int ni = 0; ni < 4; ++ni) {
          int col = n0 + wn + ni * 16 + r;
#pragma unroll
          for (int j = 0; j < 4; ++j) {
            int row = m0 + wm + mi * 16 + g * 4 + j;
            Cout[(size_t)row * 512 + col] = f2bf(acc[mi][ni][j]);
            acc[mi][ni][j] = 0.f;
          }
        }
    }
  }
#undef STAGE_
#undef ADV_
}

// ---------------- scan pass A: per-chunk carries (interleaved Bu) ----------
__global__ __launch_bounds__(256) void scan_carry(const unsigned short* __restrict__ Bu,
                                                  const float* __restrict__ lam,
                                                  float* __restrict__ carry) {
  int bid = blockIdx.x;              // b*128 + c
  int b = bid >> 7, c = bid & 127;
  int p = threadIdx.x;
  float ar = lam[p], ai = lam[PP + p];
  float sr = 0.f, si = 0.f;
  size_t base = ((size_t)b * LL + (size_t)c * SCHUNK) * 512;
#pragma unroll
  for (int i = 0; i < SCHUNK; ++i) {
    unsigned u = ((const unsigned*)(Bu + base + (size_t)i * 512))[p];
    float ur = bf2f((unsigned short)(u & 0xFFFFu));
    float ui = bf2f((unsigned short)(u >> 16));
    float nr = ar * sr - ai * si + ur;
    float ni = ar * si + ai * sr + ui;
    sr = nr; si = ni;
  }
  ((float2*)(carry + (size_t)bid * 512))[p] = make_float2(sr, si);
}

// ---------------- fused chunk-chain: depth 128, loads prefetch ahead -------
__global__ void chain_fused(float* carry, const float* __restrict__ lam) {
  int b = blockIdx.x;                // 16
  int p = threadIdx.x;               // 256
  float ar = lam[2 * PP + p], ai = lam[3 * PP + p];   // a^32
  float sr = 0.f, si = 0.f;
  float2* c2 = ((float2*)carry) + (size_t)b * NCHUNK * 256 + p;
#pragma unroll 8
  for (int c = 0; c < NCHUNK; ++c) {
    float2 cv = c2[(size_t)c * 256];
    c2[(size_t)c * 256] = make_float2(sr, si);   // exclusive: state entering chunk c
    float nr = cv.x + ar * sr - ai * si;
    float ni = cv.y + ar * si + ai * sr;
    sr = nr; si = ni;
  }
}

// ---------------- scan pass C: recompute with carry-in, xs IN-PLACE over Bu --
__global__ __launch_bounds__(256) void scan_final(unsigned short* Bu,
                                                  const float* __restrict__ lam,
                                                  const float* __restrict__ carry) {
  int bid = blockIdx.x;
  int b = bid >> 7, c = bid & 127;
  int p = threadIdx.x;
  float ar = lam[p], ai = lam[PP + p];
  float2 s0 = ((const float2*)(carry + (size_t)bid * 512))[p];
  float sr = s0.x, si = s0.y;
  size_t base = ((size_t)b * LL + (size_t)c * SCHUNK) * 512;
#pragma unroll
  for (int i = 0; i < SCHUNK; ++i) {
    unsigned* slot = ((unsigned*)(Bu + base + (size_t)i * 512)) + p;
    unsigned u = *slot;
    float ur = bf2f((unsigned short)(u & 0xFFFFu));
    float ui = bf2f((unsigned short)(u >> 16));
    float nr = ar * sr - ai * si + ur;
    float ni = ar * si + ai * sr + ui;
    sr = nr; si = ni;
    *slot = (unsigned)f2bf(sr) | ((unsigned)f2bf(si) << 16);
  }
}

// ---------------- fused epilogue: D-skip + gelu + residual + LayerNorm ------
// ys bf16 [M,512], x f32 [M,512] (original input). One wave per row.
__global__ __launch_bounds__(256) void ln_fused(const unsigned short* __restrict__ ys,
                                                const float* __restrict__ x,
                                                const float* __restrict__ Dv,
                                                const float* __restrict__ scale,
                                                const float* __restrict__ bias,
                                                float* __restrict__ out) {
  int tid = threadIdx.x, lane = tid & 63, wv = tid >> 6;
  int gw = blockIdx.x * 4 + wv;      // 0..8191
  int c0 = lane * 8;
  float sc[8], bi[8], Dh[8];
#pragma unroll
  for (int j = 0; j < 8; ++j) {
    sc[j] = scale[c0 + j]; bi[j] = bias[c0 + j]; Dh[j] = Dv[c0 + j];
  }
  for (int row = gw; row < MM; row += 8192) {
    uint4 yv = *(const uint4*)(ys + (size_t)row * 512 + c0);
    float yf[8];
    yf[0] = bf2f((unsigned short)(yv.x & 0xFFFFu)); yf[1] = bf2f((unsigned short)(yv.x >> 16));
    yf[2] = bf2f((unsigned short)(yv.y & 0xFFFFu)); yf[3] = bf2f((unsigned short)(yv.y >> 16));
    yf[4] = bf2f((unsigned short)(yv.z & 0xFFFFu)); yf[5] = bf2f((unsigned short)(yv.z >> 16));
    yf[6] = bf2f((unsigned short)(yv.w & 0xFFFFu)); yf[7] = bf2f((unsigned short)(yv.w >> 16));
    const float4* xp = (const float4*)(x + (size_t)row * 512 + c0);
    float4 xv0 = xp[0], xv1 = xp[1];
    float xf[8] = {xv0.x, xv0.y, xv0.z, xv0.w, xv1.x, xv1.y, xv1.z, xv1.w};
    float zf[8];
    float s = 0.f, s2 = 0.f;
#pragma unroll
    for (int j = 0; j < 8; ++j) {
      float t = yf[j] + xf[j] * Dh[j];
      float u2 = 0.7978845608028654f * (t + 0.044715f * t * t * t);
      float e = __expf(2.f * u2);
      float th = 1.f - 2.f / (e + 1.f);
      float y = 0.5f * t * (1.f + th);
      float z = xf[j] + y;
      zf[j] = z;
      s += z; s2 += z * z;
    }
#pragma unroll
    for (int o = 32; o; o >>= 1) {
      s += __shfl_xor(s, o, 64);
      s2 += __shfl_xor(s2, o, 64);
    }
    float mean = s * (1.f / 512.f);
    float var = s2 * (1.f / 512.f) - mean * mean;
    float inv = rsqrtf(var + 1e-6f);
    float o8[8];
#pragma unroll
    for (int j = 0; j < 8; ++j) o8[j] = (zf[j] - mean) * inv * sc[j] + bi[j];
    float4* op = (float4*)(out + (size_t)row * 512 + c0);
    op[0] = make_float4(o8[0], o8[1], o8[2], o8[3]);
    op[1] = make_float4(o8[4], o8[5], o8[6], o8[7]);
  }
}

// ---------------- launcher ----------------
extern "C" void kernel_launch(void* const* d_in, const int* in_sizes, int n_in,
                              void* d_out, int out_size, void* d_ws, size_t ws_size,
                              hipStream_t stream) {
  const float* x    = (const float*)d_in[0];
  const float* llr  = (const float*)d_in[1];
  const float* lim  = (const float*)d_in[2];
  const float* B_re = (const float*)d_in[3];
  const float* B_im = (const float*)d_in[4];
  const float* C_re = (const float*)d_in[5];
  const float* C_im = (const float*)d_in[6];
  const float* Dv   = (const float*)d_in[7];
  const float* lstep= (const float*)d_in[8];
  const float* lnsc = (const float*)d_in[9];
  const float* lnbi = (const float*)d_in[10];
  float* out = (float*)d_out;

  char* ws = (char*)d_ws;
  // layout:
  //   [0, 64MB)        x_bf16 (GEMM1 A) -> reused as ys (GEMM2 out)
  //   [64MB, 128MB)    Bu bf16 (interleaved re/im) -> xs in-place
  //   bcat 512KB, ccat 512KB, lam 8KB, carry 4MB
  unsigned short* xb   = (unsigned short*)(ws);
  unsigned short* bu   = (unsigned short*)(ws + 67108864);
  unsigned short* bcat = (unsigned short*)(ws + 134217728);
  unsigned short* ccat = (unsigned short*)(ws + 134742016);
  float* lam           = (float*)(ws + 135266304);
  float* carry         = (float*)(ws + 135274496);

  precompute_params<<<1, 256, 0, stream>>>(llr, lim, lstep, lam);
  build_weights<<<1024, 256, 0, stream>>>(B_re, B_im, C_re, C_im, lam, bcat, ccat);
  cvt_x_bf16<<<2048, 256, 0, stream>>>(x, xb);
  gemm_bt<<<512, 256, 0, stream>>>(xb, bcat, bu);           // Bu = x @ Bcat^T
  scan_carry<<<2048, 256, 0, stream>>>(bu, lam, carry);
  chain_fused<<<16, 256, 0, stream>>>(carry, lam);
  scan_final<<<2048, 256, 0, stream>>>(bu, lam, carry);     // xs in-place over Bu
  gemm_bt<<<512, 256, 0, stream>>>(bu, ccat, xb);           // ys = xs @ Ccat^T (over xb)
  ln_fused<<<2048, 256, 0, stream>>>(xb, x, Dv, lnsc, lnbi, out);
}